// Round 4
// baseline (402.494 us; speedup 1.0000x reference)
//
#include <hip/hip_runtime.h>

typedef unsigned short u16;
typedef __bf16 bf16x8 __attribute__((ext_vector_type(8)));
typedef float f32x4 __attribute__((ext_vector_type(4)));

#define BB 2
#define TT 2048
#define CC 1024
#define HH 16
#define DD 64
#define MM (BB*TT)   // 4096

__device__ __forceinline__ u16 f2b(float f) {
    union { float f; unsigned int i; } a; a.f = f;
    unsigned int u = a.i;
    unsigned int r = (u + 0x7FFFu + ((u >> 16) & 1u)) >> 16;
    return (u16)r;
}

// ---------------- fp32 -> bf16 elementwise ----------------
__global__ __launch_bounds__(256) void cvt_x_k(const float* __restrict__ in,
                                               u16* __restrict__ out) {
    int i = blockIdx.x * 256 + threadIdx.x;
    float4 v = ((const float4*)in)[i];
    ushort4 o;
    o.x = f2b(v.x); o.y = f2b(v.y); o.z = f2b(v.z); o.w = f2b(v.w);
    ((ushort4*)out)[i] = o;
}

// ------ fp32 [K,N] -> bf16 [N,K] transpose+convert: out[n*K+k]=in[k*N+n] ------
__global__ __launch_bounds__(256) void transpose_cvt_k(const float* __restrict__ in,
                                                       u16* __restrict__ out,
                                                       int K, int N) {
    __shared__ u16 tile[64][65];
    int n0 = blockIdx.x * 64, k0 = blockIdx.y * 64;
    int tx = threadIdx.x, ty = threadIdx.y;   // (64,4)
    for (int i = 0; i < 16; i++) {
        int row = ty + i * 4;
        tile[row][tx] = f2b(in[(size_t)(k0 + row) * N + n0 + tx]);
    }
    __syncthreads();
    for (int i = 0; i < 16; i++) {
        int row = ty + i * 4;
        out[(size_t)(n0 + row) * K + k0 + tx] = tile[tx][row];
    }
}

// ---------------- GEMM: C[M,N] = A[M,K] * Bt[N,K]^T ----------------
// MODE 0: A = xb [4096,1024] bf16; scatter C -> q/k/v [B*H, T, D] bf16
// MODE 1: A = y_att gathered from [B*H, T, D] bf16; C -> out [4096,1024] fp32
template<int MODE>
__global__ __launch_bounds__(256) void gemm_k(const u16* __restrict__ A,
                                              const u16* __restrict__ Bt,
                                              u16* __restrict__ Cq,
                                              u16* __restrict__ Ck,
                                              u16* __restrict__ Cv,
                                              float* __restrict__ Cout,
                                              int N, int K) {
    __shared__ __attribute__((aligned(16))) u16 As[128 * 32];
    __shared__ __attribute__((aligned(16))) u16 Bs[128 * 32];
    const int tid  = threadIdx.x;
    const int lane = tid & 63, w = tid >> 6;
    const int wm = w >> 1, wn = w & 1;
    const int quad = lane >> 4, l16 = lane & 15;
    const int m0 = blockIdx.x * 128, n0 = blockIdx.y * 128;

    f32x4 acc[4][4];
    for (int mi = 0; mi < 4; mi++)
        for (int ni = 0; ni < 4; ni++)
            for (int e = 0; e < 4; e++) acc[mi][ni][e] = 0.f;

    for (int k0 = 0; k0 < K; k0 += 32) {
        for (int i = 0; i < 2; i++) {
            int c = tid + 256 * i;          // 512 chunks of 8 elems
            int row = c >> 2, col = (c & 3) * 8;
            const u16* srcA;
            if constexpr (MODE == 0) {
                srcA = A + (size_t)(m0 + row) * K + k0 + col;
            } else {
                int m = m0 + row;
                int b = m >> 11, t = m & 2047;
                int kk = k0 + col;           // within one head (64 | 32-tile)
                int h = kk >> 6, d = kk & 63;
                srcA = A + ((size_t)(b * HH + h) * TT + t) * DD + d;
            }
            *(int4*)(&As[row * 32 + col]) = *(const int4*)srcA;
            *(int4*)(&Bs[row * 32 + col]) =
                *(const int4*)(Bt + (size_t)(n0 + row) * K + k0 + col);
        }
        __syncthreads();
        bf16x8 af[4], bfm[4];
        for (int mi = 0; mi < 4; mi++)
            af[mi] = *(const bf16x8*)&As[(wm * 64 + mi * 16 + l16) * 32 + quad * 8];
        for (int ni = 0; ni < 4; ni++)
            bfm[ni] = *(const bf16x8*)&Bs[(wn * 64 + ni * 16 + l16) * 32 + quad * 8];
        for (int mi = 0; mi < 4; mi++)
            for (int ni = 0; ni < 4; ni++)
                acc[mi][ni] = __builtin_amdgcn_mfma_f32_16x16x32_bf16(
                    af[mi], bfm[ni], acc[mi][ni], 0, 0, 0);
        __syncthreads();
    }

    for (int mi = 0; mi < 4; mi++)
        for (int ni = 0; ni < 4; ni++)
            for (int r = 0; r < 4; r++) {
                int row = m0 + wm * 64 + mi * 16 + quad * 4 + r;
                int col = n0 + wn * 64 + ni * 16 + l16;
                if constexpr (MODE == 0) {
                    int which = col >> 10;           // 0=q 1=k 2=v
                    int h = (col >> 6) & 15, d = col & 63;
                    int b = row >> 11, t = row & 2047;
                    size_t off = ((size_t)(b * HH + h) * TT + t) * DD + d;
                    (which == 0 ? Cq : which == 1 ? Ck : Cv)[off] = f2b(acc[mi][ni][r]);
                } else {
                    Cout[(size_t)row * N + col] = acc[mi][ni][r];
                }
            }
}

// ---------------- flash attention over [B*H, T, D] bf16 ----------------
__global__ __launch_bounds__(256) void attn_k(const u16* __restrict__ Q,
                                              const u16* __restrict__ Kb,
                                              const u16* __restrict__ Vb,
                                              u16* __restrict__ Y) {
    __shared__ __attribute__((aligned(16))) u16 Ks[64 * 64];
    __shared__ __attribute__((aligned(16))) u16 Vt[64 * 64];   // transposed: Vt[d][k]
    __shared__ __attribute__((aligned(16))) u16 Ps[4 * 16 * 64];
    const int tid  = threadIdx.x;
    const int lane = tid & 63, w = tid >> 6;
    const int quad = lane >> 4, l16 = lane & 15;
    const int qt = blockIdx.x;      // 64-row q tile
    const int bh = blockIdx.y;
    const int q0 = qt * 64;
    const size_t base = (size_t)bh * TT * DD;

    // preload Q fragments (16 rows per wave), A-layout
    bf16x8 qf[2];
    {
        const u16* qrow = Q + base + (size_t)(q0 + w * 16 + l16) * DD;
        qf[0] = *(const bf16x8*)(qrow + quad * 8);
        qf[1] = *(const bf16x8*)(qrow + 32 + quad * 8);
    }

    float mst[4], lst[4];
    f32x4 oacc[4];
    for (int r = 0; r < 4; r++) { mst[r] = -1e30f; lst[r] = 0.f; }
    for (int nd = 0; nd < 4; nd++)
        for (int e = 0; e < 4; e++) oacc[nd][e] = 0.f;

    for (int jt = 0; jt <= qt; jt++) {
        const int k0 = jt * 64;
        // stage K tile (row-major, contiguous copy)
        for (int i = 0; i < 2; i++) {
            int c = tid + 256 * i;     // 512 x 8 elems
            *(int4*)&Ks[c * 8] = *(const int4*)(Kb + base + (size_t)k0 * DD + c * 8);
        }
        // stage V tile transposed
        for (int i = 0; i < 4; i++) {
            int c = tid + 256 * i;     // 1024 x 4 elems
            int kr = c >> 4, d4 = (c & 15) * 4;
            ushort4 vv = *(const ushort4*)(Vb + base + (size_t)(k0 + kr) * DD + d4);
            Vt[(d4 + 0) * 64 + kr] = vv.x;
            Vt[(d4 + 1) * 64 + kr] = vv.y;
            Vt[(d4 + 2) * 64 + kr] = vv.z;
            Vt[(d4 + 3) * 64 + kr] = vv.w;
        }
        __syncthreads();

        // S = Q K^T (wave: 16 q-rows x 64 k-cols)
        f32x4 sacc[4];
        for (int ni = 0; ni < 4; ni++)
            for (int e = 0; e < 4; e++) sacc[ni][e] = 0.f;
        for (int kk = 0; kk < 2; kk++)
            for (int ni = 0; ni < 4; ni++) {
                bf16x8 kf = *(const bf16x8*)&Ks[(ni * 16 + l16) * 64 + kk * 32 + quad * 8];
                sacc[ni] = __builtin_amdgcn_mfma_f32_16x16x32_bf16(
                    qf[kk], kf, sacc[ni], 0, 0, 0);
            }

        float s[4][4];
        for (int ni = 0; ni < 4; ni++)
            for (int r = 0; r < 4; r++) s[ni][r] = sacc[ni][r] * 0.125f;
        if (jt == qt) {   // diagonal tile: causal mask (local coords, k0==q0)
            for (int ni = 0; ni < 4; ni++)
                for (int r = 0; r < 4; r++) {
                    int row = w * 16 + quad * 4 + r;
                    int col = ni * 16 + l16;
                    if (col > row) s[ni][r] = -1e30f;
                }
        }

        // online softmax update
        float mnew[4], alpha[4];
        for (int r = 0; r < 4; r++) {
            float mx = fmaxf(fmaxf(s[0][r], s[1][r]), fmaxf(s[2][r], s[3][r]));
            for (int off = 8; off >= 1; off >>= 1)
                mx = fmaxf(mx, __shfl_xor(mx, off));
            mnew[r]  = fmaxf(mst[r], mx);
            alpha[r] = __expf(mst[r] - mnew[r]);
            mst[r]   = mnew[r];
        }
        float p[4][4];
        for (int ni = 0; ni < 4; ni++)
            for (int r = 0; r < 4; r++) p[ni][r] = __expf(s[ni][r] - mnew[r]);
        for (int r = 0; r < 4; r++) {
            float sm = p[0][r] + p[1][r] + p[2][r] + p[3][r];
            for (int off = 8; off >= 1; off >>= 1)
                sm += __shfl_xor(sm, off);
            lst[r] = lst[r] * alpha[r] + sm;
        }
        for (int nd = 0; nd < 4; nd++)
            for (int r = 0; r < 4; r++) oacc[nd][r] *= alpha[r];

        // P (C-layout) -> LDS, bf16
        for (int ni = 0; ni < 4; ni++)
            for (int r = 0; r < 4; r++)
                Ps[w * 1024 + (quad * 4 + r) * 64 + ni * 16 + l16] = f2b(p[ni][r]);
        __syncthreads();

        // O += P V
        for (int kk = 0; kk < 2; kk++) {
            bf16x8 pf = *(const bf16x8*)&Ps[w * 1024 + l16 * 64 + kk * 32 + quad * 8];
            for (int nd = 0; nd < 4; nd++) {
                bf16x8 vf = *(const bf16x8*)&Vt[(nd * 16 + l16) * 64 + kk * 32 + quad * 8];
                oacc[nd] = __builtin_amdgcn_mfma_f32_16x16x32_bf16(
                    pf, vf, oacc[nd], 0, 0, 0);
            }
        }
        __syncthreads();
    }

    for (int nd = 0; nd < 4; nd++)
        for (int r = 0; r < 4; r++) {
            int row = q0 + w * 16 + quad * 4 + r;
            int col = nd * 16 + l16;
            Y[base + (size_t)row * DD + col] = f2b(oacc[nd][r] / lst[r]);
        }
}

extern "C" void kernel_launch(void* const* d_in, const int* in_sizes, int n_in,
                              void* d_out, int out_size, void* d_ws, size_t ws_size,
                              hipStream_t stream) {
    const float* x      = (const float*)d_in[0];   // [2,2048,1024] fp32
    const float* W_attn = (const float*)d_in[1];   // [1024,3072]  fp32
    const float* W_proj = (const float*)d_in[2];   // [1024,1024]  fp32
    float* out = (float*)d_out;                    // [2,2048,1024] fp32

    // workspace layout (~48 MB), all bf16
    u16* Wt_attn = (u16*)d_ws;                    // 3072*1024
    u16* Wt_proj = Wt_attn + 3072 * 1024;         // 1024*1024
    u16* xb      = Wt_proj + 1024 * 1024;         // 4096*1024
    u16* q       = xb + (size_t)MM * CC;          // 32*2048*64
    u16* k       = q + (size_t)32 * 2048 * 64;
    u16* v       = k + (size_t)32 * 2048 * 64;
    u16* y       = v + (size_t)32 * 2048 * 64;

    cvt_x_k<<<dim3(MM * CC / 1024), 256, 0, stream>>>(x, xb);
    transpose_cvt_k<<<dim3(3072 / 64, 1024 / 64), dim3(64, 4), 0, stream>>>(
        W_attn, Wt_attn, 1024, 3072);
    transpose_cvt_k<<<dim3(1024 / 64, 1024 / 64), dim3(64, 4), 0, stream>>>(
        W_proj, Wt_proj, 1024, 1024);
    gemm_k<0><<<dim3(MM / 128, 3072 / 128), 256, 0, stream>>>(
        xb, Wt_attn, q, k, v, nullptr, 3072, 1024);
    attn_k<<<dim3(TT / 64, BB * HH), 256, 0, stream>>>(q, k, v, y);
    gemm_k<1><<<dim3(MM / 128, 1024 / 128), 256, 0, stream>>>(
        y, Wt_proj, nullptr, nullptr, nullptr, out, 1024, 1024);
}

// Round 5
// 336.541 us; speedup vs baseline: 1.1960x; 1.1960x over previous
//
#include <hip/hip_runtime.h>

typedef unsigned short u16;
typedef __bf16 bf16x8 __attribute__((ext_vector_type(8)));
typedef float f32x4 __attribute__((ext_vector_type(4)));

#define BB 2
#define TT 2048
#define CC 1024
#define HH 16
#define DD 64
#define MM (BB*TT)   // 4096

__device__ __forceinline__ u16 f2b(float f) {
    union { float f; unsigned int i; } a; a.f = f;
    unsigned int u = a.i;
    unsigned int r = (u + 0x7FFFu + ((u >> 16) & 1u)) >> 16;
    return (u16)r;
}
// fast round (half-away) — used only for P in [0,1]
__device__ __forceinline__ u16 f2b_fast(float f) {
    union { float f; unsigned int i; } a; a.f = f;
    return (u16)((a.i + 0x8000u) >> 16);
}

// ---------------- fp32 -> bf16 elementwise ----------------
__global__ __launch_bounds__(256) void cvt_x_k(const float* __restrict__ in,
                                               u16* __restrict__ out) {
    int i = blockIdx.x * 256 + threadIdx.x;
    float4 v = ((const float4*)in)[i];
    ushort4 o;
    o.x = f2b(v.x); o.y = f2b(v.y); o.z = f2b(v.z); o.w = f2b(v.w);
    ((ushort4*)out)[i] = o;
}

// ------ fp32 [K,N] -> bf16 [N,K] transpose+convert: out[n*K+k]=in[k*N+n] ------
__global__ __launch_bounds__(256) void transpose_cvt_k(const float* __restrict__ in,
                                                       u16* __restrict__ out,
                                                       int K, int N) {
    __shared__ u16 tile[64][65];
    int n0 = blockIdx.x * 64, k0 = blockIdx.y * 64;
    int tx = threadIdx.x, ty = threadIdx.y;   // (64,4)
    for (int i = 0; i < 16; i++) {
        int row = ty + i * 4;
        tile[row][tx] = f2b(in[(size_t)(k0 + row) * N + n0 + tx]);
    }
    __syncthreads();
    for (int i = 0; i < 16; i++) {
        int row = ty + i * 4;
        out[(size_t)(n0 + row) * K + k0 + tx] = tile[tx][row];
    }
}

// ------ bf16 per-bh transpose: v[bh][T][D] -> vt[bh][D][T] ------
__global__ __launch_bounds__(256) void transpose_v_k(const u16* __restrict__ in,
                                                     u16* __restrict__ out) {
    __shared__ u16 tile[64][65];
    int t0 = blockIdx.x * 64, bh = blockIdx.y;
    const u16* src = in + (size_t)bh * TT * DD;
    u16* dst = out + (size_t)bh * DD * TT;
    int tx = threadIdx.x, ty = threadIdx.y;   // (64,4)
    for (int i = 0; i < 16; i++) {
        int row = ty + i * 4;                 // t within tile
        tile[row][tx] = src[(size_t)(t0 + row) * DD + tx];
    }
    __syncthreads();
    for (int i = 0; i < 16; i++) {
        int row = ty + i * 4;                 // d
        dst[(size_t)row * TT + t0 + tx] = tile[tx][row];
    }
}

// ---------------- GEMM: C[M,N] = A[M,K] * Bt[N,K]^T ----------------
template<int MODE>
__global__ __launch_bounds__(256) void gemm_k(const u16* __restrict__ A,
                                              const u16* __restrict__ Bt,
                                              u16* __restrict__ Cq,
                                              u16* __restrict__ Ck,
                                              u16* __restrict__ Cv,
                                              float* __restrict__ Cout,
                                              int N, int K) {
    __shared__ __attribute__((aligned(16))) u16 As[128 * 32];
    __shared__ __attribute__((aligned(16))) u16 Bs[128 * 32];
    const int tid  = threadIdx.x;
    const int lane = tid & 63, w = tid >> 6;
    const int wm = w >> 1, wn = w & 1;
    const int quad = lane >> 4, l16 = lane & 15;
    const int m0 = blockIdx.x * 128, n0 = blockIdx.y * 128;

    f32x4 acc[4][4];
    for (int mi = 0; mi < 4; mi++)
        for (int ni = 0; ni < 4; ni++)
            for (int e = 0; e < 4; e++) acc[mi][ni][e] = 0.f;

    for (int k0 = 0; k0 < K; k0 += 32) {
        for (int i = 0; i < 2; i++) {
            int c = tid + 256 * i;
            int row = c >> 2, col = (c & 3) * 8;
            const u16* srcA;
            if constexpr (MODE == 0) {
                srcA = A + (size_t)(m0 + row) * K + k0 + col;
            } else {
                int m = m0 + row;
                int b = m >> 11, t = m & 2047;
                int kk = k0 + col;
                int h = kk >> 6, d = kk & 63;
                srcA = A + ((size_t)(b * HH + h) * TT + t) * DD + d;
            }
            *(int4*)(&As[row * 32 + col]) = *(const int4*)srcA;
            *(int4*)(&Bs[row * 32 + col]) =
                *(const int4*)(Bt + (size_t)(n0 + row) * K + k0 + col);
        }
        __syncthreads();
        bf16x8 af[4], bfm[4];
        for (int mi = 0; mi < 4; mi++)
            af[mi] = *(const bf16x8*)&As[(wm * 64 + mi * 16 + l16) * 32 + quad * 8];
        for (int ni = 0; ni < 4; ni++)
            bfm[ni] = *(const bf16x8*)&Bs[(wn * 64 + ni * 16 + l16) * 32 + quad * 8];
        for (int mi = 0; mi < 4; mi++)
            for (int ni = 0; ni < 4; ni++)
                acc[mi][ni] = __builtin_amdgcn_mfma_f32_16x16x32_bf16(
                    af[mi], bfm[ni], acc[mi][ni], 0, 0, 0);
        __syncthreads();
    }

    for (int mi = 0; mi < 4; mi++)
        for (int ni = 0; ni < 4; ni++)
            for (int r = 0; r < 4; r++) {
                int row = m0 + wm * 64 + mi * 16 + quad * 4 + r;
                int col = n0 + wn * 64 + ni * 16 + l16;
                if constexpr (MODE == 0) {
                    int which = col >> 10;
                    int h = (col >> 6) & 15, d = col & 63;
                    int b = row >> 11, t = row & 2047;
                    size_t off = ((size_t)(b * HH + h) * TT + t) * DD + d;
                    (which == 0 ? Cq : which == 1 ? Ck : Cv)[off] = f2b(acc[mi][ni][r]);
                } else {
                    Cout[(size_t)row * N + col] = acc[mi][ni][r];
                }
            }
}

// ---------------- flash attention v2: 128x128 tiles, swizzled LDS ----------------
// Q,K: [bh][T][D]; Vt: [bh][D][T]; Y: [bh][T][D]
__global__ __launch_bounds__(256) void attn_k(const u16* __restrict__ Q,
                                              const u16* __restrict__ Kb,
                                              const u16* __restrict__ Vtg,
                                              u16* __restrict__ Y) {
    // swizzle: elem(row,col) at row*RS + (((col>>3) ^ (row & GM)) << 3) + (col&7)
    __shared__ __attribute__((aligned(16))) u16 Ks[128 * 64];        // [kcol][d], GM=7
    __shared__ __attribute__((aligned(16))) u16 Vs[64 * 128];        // [d][t],   GM=15
    __shared__ __attribute__((aligned(16))) u16 Ps[4][32 * 128];     // per-wave [qrow][t], GM=15
    const int tid  = threadIdx.x;
    const int lane = tid & 63, w = tid >> 6;
    const int quad = lane >> 4, l16 = lane & 15;
    const int bh = blockIdx.y;
    const int qx = blockIdx.x;                 // heavy+light pairing
    const int qt = (qx & 1) ? (15 - (qx >> 1)) : (qx >> 1);
    const int q0 = qt * 128;
    const size_t base  = (size_t)bh * TT * DD;     // Q,K,Y
    const size_t baseV = (size_t)bh * DD * TT;     // Vt

    // Q fragments: wave rows q0 + w*32 + mi*16 + l16
    bf16x8 qf[2][2];
    for (int mi = 0; mi < 2; mi++)
        for (int kk = 0; kk < 2; kk++)
            qf[mi][kk] = *(const bf16x8*)(Q + base +
                (size_t)(q0 + w * 32 + mi * 16 + l16) * DD + kk * 32 + quad * 8);

    float mst[2][4], lst[2][4];
    f32x4 oacc[2][4];
    for (int mi = 0; mi < 2; mi++)
        for (int r = 0; r < 4; r++) { mst[mi][r] = -1e30f; lst[mi][r] = 0.f; }
    for (int mi = 0; mi < 2; mi++)
        for (int nd = 0; nd < 4; nd++)
            for (int e = 0; e < 4; e++) oacc[mi][nd][e] = 0.f;

    const float SC = 0.125f * 1.44269504f;     // 1/sqrt(D) * log2(e)

    for (int jt = 0; jt <= qt; jt++) {
        const int k0 = jt * 128;
        // stage K tile: 128 rows(kcol) x 64(d), 8-granule swizzle
        for (int i = 0; i < 4; i++) {
            int c = i * 256 + tid;             // 1024 int4 chunks
            int r = c >> 3, g = c & 7;
            int4 val = *(const int4*)(Kb + base + (size_t)(k0 + r) * DD + g * 8);
            *(int4*)&Ks[r * 64 + (((g ^ (r & 7)) << 3))] = val;
        }
        // stage Vt tile: 64 rows(d) x 128(t), 16-granule swizzle
        for (int i = 0; i < 4; i++) {
            int c = i * 256 + tid;
            int r = c >> 4, g = c & 15;
            int4 val = *(const int4*)(Vtg + baseV + (size_t)r * TT + k0 + g * 8);
            *(int4*)&Vs[r * 128 + (((g ^ (r & 15)) << 3))] = val;
        }
        __syncthreads();

        // S = Q K^T : per wave 32 q-rows x 128 k-cols
        f32x4 sacc[2][8];
        for (int mi = 0; mi < 2; mi++)
            for (int ni = 0; ni < 8; ni++)
                for (int e = 0; e < 4; e++) sacc[mi][ni][e] = 0.f;
        for (int kk = 0; kk < 2; kk++)
            for (int ni = 0; ni < 8; ni++) {
                int row = ni * 16 + l16;
                bf16x8 kf = *(const bf16x8*)&Ks[row * 64 +
                    (((kk * 4 + quad) ^ (row & 7)) << 3)];
                sacc[0][ni] = __builtin_amdgcn_mfma_f32_16x16x32_bf16(
                    qf[0][kk], kf, sacc[0][ni], 0, 0, 0);
                sacc[1][ni] = __builtin_amdgcn_mfma_f32_16x16x32_bf16(
                    qf[1][kk], kf, sacc[1][ni], 0, 0, 0);
            }

        // scale into log2 domain + causal mask on diagonal tile
        for (int mi = 0; mi < 2; mi++)
            for (int ni = 0; ni < 8; ni++)
                for (int r = 0; r < 4; r++) sacc[mi][ni][r] *= SC;
        if (jt == qt) {
            for (int mi = 0; mi < 2; mi++)
                for (int ni = 0; ni < 8; ni++)
                    for (int r = 0; r < 4; r++) {
                        int rowl = w * 32 + mi * 16 + quad * 4 + r;
                        int coll = ni * 16 + l16;
                        if (coll > rowl) sacc[mi][ni][r] = -1e30f;
                    }
        }

        // online softmax (log2 domain)
        float alpha[2][4], mnew[2][4];
        for (int mi = 0; mi < 2; mi++)
            for (int r = 0; r < 4; r++) {
                float mx = sacc[mi][0][r];
                for (int ni = 1; ni < 8; ni++) mx = fmaxf(mx, sacc[mi][ni][r]);
                for (int off = 8; off >= 1; off >>= 1)
                    mx = fmaxf(mx, __shfl_xor(mx, off));
                mnew[mi][r]  = fmaxf(mst[mi][r], mx);
                alpha[mi][r] = __builtin_amdgcn_exp2f(mst[mi][r] - mnew[mi][r]);
                mst[mi][r]   = mnew[mi][r];
            }
        float rowsum[2][4];
        for (int mi = 0; mi < 2; mi++)
            for (int r = 0; r < 4; r++) rowsum[mi][r] = 0.f;
        for (int mi = 0; mi < 2; mi++)
            for (int ni = 0; ni < 8; ni++)
                for (int r = 0; r < 4; r++) {
                    float p = __builtin_amdgcn_exp2f(sacc[mi][ni][r] - mnew[mi][r]);
                    rowsum[mi][r] += p;
                    int row = mi * 16 + quad * 4 + r;       // logical Ps row (0..31)
                    int cg  = ni * 2 + (l16 >> 3);          // col granule
                    Ps[w][row * 128 + (((cg ^ (row & 15)) << 3)) + (l16 & 7)] =
                        f2b_fast(p);
                }
        for (int mi = 0; mi < 2; mi++)
            for (int r = 0; r < 4; r++) {
                float sm = rowsum[mi][r];
                for (int off = 8; off >= 1; off >>= 1)
                    sm += __shfl_xor(sm, off);
                lst[mi][r] = lst[mi][r] * alpha[mi][r] + sm;
            }
        for (int mi = 0; mi < 2; mi++)
            for (int nd = 0; nd < 4; nd++)
                for (int r = 0; r < 4; r++) oacc[mi][nd][r] *= alpha[mi][r];

        // O += P V  (Ps is per-wave: no barrier needed; DS ops are in-order per wave)
        for (int kk = 0; kk < 4; kk++) {
            bf16x8 pf[2];
            for (int mi = 0; mi < 2; mi++) {
                int row = mi * 16 + l16;
                pf[mi] = *(const bf16x8*)&Ps[w][row * 128 +
                    (((kk * 4 + quad) ^ (row & 15)) << 3)];
            }
            for (int nd = 0; nd < 4; nd++) {
                int row = nd * 16 + l16;
                bf16x8 vf = *(const bf16x8*)&Vs[row * 128 +
                    (((kk * 4 + quad) ^ (row & 15)) << 3)];
                oacc[0][nd] = __builtin_amdgcn_mfma_f32_16x16x32_bf16(
                    pf[0], vf, oacc[0][nd], 0, 0, 0);
                oacc[1][nd] = __builtin_amdgcn_mfma_f32_16x16x32_bf16(
                    pf[1], vf, oacc[1][nd], 0, 0, 0);
            }
        }
        __syncthreads();
    }

    for (int mi = 0; mi < 2; mi++)
        for (int nd = 0; nd < 4; nd++)
            for (int r = 0; r < 4; r++) {
                int row = q0 + w * 32 + mi * 16 + quad * 4 + r;
                int col = nd * 16 + l16;
                Y[base + (size_t)row * DD + col] =
                    f2b(oacc[mi][nd][r] / lst[mi][r]);
            }
}

extern "C" void kernel_launch(void* const* d_in, const int* in_sizes, int n_in,
                              void* d_out, int out_size, void* d_ws, size_t ws_size,
                              hipStream_t stream) {
    const float* x      = (const float*)d_in[0];   // [2,2048,1024] fp32
    const float* W_attn = (const float*)d_in[1];   // [1024,3072]  fp32
    const float* W_proj = (const float*)d_in[2];   // [1024,1024]  fp32
    float* out = (float*)d_out;                    // [2,2048,1024] fp32

    // workspace layout (~48 MB), all bf16
    u16* Wt_attn = (u16*)d_ws;                    // 3072*1024
    u16* Wt_proj = Wt_attn + 3072 * 1024;         // 1024*1024
    u16* xb      = Wt_proj + 1024 * 1024;         // 4096*1024 (reused as vt after gemm0)
    u16* q       = xb + (size_t)MM * CC;          // 32*2048*64
    u16* k       = q + (size_t)32 * 2048 * 64;
    u16* v       = k + (size_t)32 * 2048 * 64;
    u16* y       = v + (size_t)32 * 2048 * 64;
    u16* vt      = xb;                            // dead after gemm<0>; 8 MB fits exactly

    cvt_x_k<<<dim3(MM * CC / 1024), 256, 0, stream>>>(x, xb);
    transpose_cvt_k<<<dim3(3072 / 64, 1024 / 64), dim3(64, 4), 0, stream>>>(
        W_attn, Wt_attn, 1024, 3072);
    transpose_cvt_k<<<dim3(1024 / 64, 1024 / 64), dim3(64, 4), 0, stream>>>(
        W_proj, Wt_proj, 1024, 1024);
    gemm_k<0><<<dim3(MM / 128, 3072 / 128), 256, 0, stream>>>(
        xb, Wt_attn, q, k, v, nullptr, 3072, 1024);
    transpose_v_k<<<dim3(TT / 64, BB * HH), dim3(64, 4), 0, stream>>>(v, vt);
    attn_k<<<dim3(TT / 128, BB * HH), 256, 0, stream>>>(q, k, vt, y);
    gemm_k<1><<<dim3(MM / 128, 1024 / 128), 256, 0, stream>>>(
        y, Wt_proj, nullptr, nullptr, nullptr, out, 1024, 1024);
}

// Round 6
// 285.645 us; speedup vs baseline: 1.4091x; 1.1782x over previous
//
#include <hip/hip_runtime.h>

typedef unsigned short u16;
typedef __bf16 bf16x8 __attribute__((ext_vector_type(8)));
typedef float f32x4 __attribute__((ext_vector_type(4)));

#define BB 2
#define TT 2048
#define CC 1024
#define HH 16
#define DD 64
#define MM (BB*TT)   // 4096

__device__ __forceinline__ u16 f2b(float f) {
    union { float f; unsigned int i; } a; a.f = f;
    unsigned int u = a.i;
    unsigned int r = (u + 0x7FFFu + ((u >> 16) & 1u)) >> 16;
    return (u16)r;
}
__device__ __forceinline__ u16 f2b_fast(float f) {
    union { float f; unsigned int i; } a; a.f = f;
    return (u16)((a.i + 0x8000u) >> 16);
}

// ---------------- fp32 -> bf16 elementwise ----------------
__global__ __launch_bounds__(256) void cvt_x_k(const float* __restrict__ in,
                                               u16* __restrict__ out) {
    int i = blockIdx.x * 256 + threadIdx.x;
    float4 v = ((const float4*)in)[i];
    ushort4 o;
    o.x = f2b(v.x); o.y = f2b(v.y); o.z = f2b(v.z); o.w = f2b(v.w);
    ((ushort4*)out)[i] = o;
}

// ------ fp32 [K,N] -> bf16 [N,K] transpose+convert ------
__global__ __launch_bounds__(256) void transpose_cvt_k(const float* __restrict__ in,
                                                       u16* __restrict__ out,
                                                       int K, int N) {
    __shared__ u16 tile[64][65];
    int n0 = blockIdx.x * 64, k0 = blockIdx.y * 64;
    int tx = threadIdx.x, ty = threadIdx.y;   // (64,4)
    for (int i = 0; i < 16; i++) {
        int row = ty + i * 4;
        tile[row][tx] = f2b(in[(size_t)(k0 + row) * N + n0 + tx]);
    }
    __syncthreads();
    for (int i = 0; i < 16; i++) {
        int row = ty + i * 4;
        out[(size_t)(n0 + row) * K + k0 + tx] = tile[tx][row];
    }
}

// ------ bf16 per-bh transpose: v[bh][T][D] -> vt[bh][D][T] ------
__global__ __launch_bounds__(256) void transpose_v_k(const u16* __restrict__ in,
                                                     u16* __restrict__ out) {
    __shared__ u16 tile[64][65];
    int t0 = blockIdx.x * 64, bh = blockIdx.y;
    const u16* src = in + (size_t)bh * TT * DD;
    u16* dst = out + (size_t)bh * DD * TT;
    int tx = threadIdx.x, ty = threadIdx.y;
    for (int i = 0; i < 16; i++) {
        int row = ty + i * 4;
        tile[row][tx] = src[(size_t)(t0 + row) * DD + tx];
    }
    __syncthreads();
    for (int i = 0; i < 16; i++) {
        int row = ty + i * 4;
        dst[(size_t)row * TT + t0 + tx] = tile[tx][row];
    }
}

// ---------------- GEMM: C[M,N] = A[M,K] * Bt[N,K]^T ----------------
template<int MODE>
__global__ __launch_bounds__(256) void gemm_k(const u16* __restrict__ A,
                                              const u16* __restrict__ Bt,
                                              u16* __restrict__ Cq,
                                              u16* __restrict__ Ck,
                                              u16* __restrict__ Cv,
                                              float* __restrict__ Cout,
                                              int N, int K) {
    __shared__ __attribute__((aligned(16))) u16 As[128 * 32];
    __shared__ __attribute__((aligned(16))) u16 Bs[128 * 32];
    const int tid  = threadIdx.x;
    const int lane = tid & 63, w = tid >> 6;
    const int wm = w >> 1, wn = w & 1;
    const int quad = lane >> 4, l16 = lane & 15;
    const int m0 = blockIdx.x * 128, n0 = blockIdx.y * 128;

    f32x4 acc[4][4];
    for (int mi = 0; mi < 4; mi++)
        for (int ni = 0; ni < 4; ni++)
            for (int e = 0; e < 4; e++) acc[mi][ni][e] = 0.f;

    for (int k0 = 0; k0 < K; k0 += 32) {
        for (int i = 0; i < 2; i++) {
            int c = tid + 256 * i;
            int row = c >> 2, col = (c & 3) * 8;
            const u16* srcA;
            if constexpr (MODE == 0) {
                srcA = A + (size_t)(m0 + row) * K + k0 + col;
            } else {
                int m = m0 + row;
                int b = m >> 11, t = m & 2047;
                int kk = k0 + col;
                int h = kk >> 6, d = kk & 63;
                srcA = A + ((size_t)(b * HH + h) * TT + t) * DD + d;
            }
            *(int4*)(&As[row * 32 + col]) = *(const int4*)srcA;
            *(int4*)(&Bs[row * 32 + col]) =
                *(const int4*)(Bt + (size_t)(n0 + row) * K + k0 + col);
        }
        __syncthreads();
        bf16x8 af[4], bfm[4];
        for (int mi = 0; mi < 4; mi++)
            af[mi] = *(const bf16x8*)&As[(wm * 64 + mi * 16 + l16) * 32 + quad * 8];
        for (int ni = 0; ni < 4; ni++)
            bfm[ni] = *(const bf16x8*)&Bs[(wn * 64 + ni * 16 + l16) * 32 + quad * 8];
        for (int mi = 0; mi < 4; mi++)
            for (int ni = 0; ni < 4; ni++)
                acc[mi][ni] = __builtin_amdgcn_mfma_f32_16x16x32_bf16(
                    af[mi], bfm[ni], acc[mi][ni], 0, 0, 0);
        __syncthreads();
    }

    for (int mi = 0; mi < 4; mi++)
        for (int ni = 0; ni < 4; ni++)
            for (int r = 0; r < 4; r++) {
                int row = m0 + wm * 64 + mi * 16 + quad * 4 + r;
                int col = n0 + wn * 64 + ni * 16 + l16;
                if constexpr (MODE == 0) {
                    int which = col >> 10;
                    int h = (col >> 6) & 15, d = col & 63;
                    int b = row >> 11, t = row & 2047;
                    size_t off = ((size_t)(b * HH + h) * TT + t) * DD + d;
                    (which == 0 ? Cq : which == 1 ? Ck : Cv)[off] = f2b(acc[mi][ni][r]);
                } else {
                    Cout[(size_t)row * N + col] = acc[mi][ni][r];
                }
            }
}

// ---------------- flash attention v3: balanced pair-blocks ----------------
// Block (p, bh) handles 64-row q-subtiles {31-p, p} of head bh.
// Passes per block = (floor((31-p)/2)+1) + (floor(p/2)+1) = 17 for ALL p.
// Q,K: [bh][T][D]; Vt: [bh][D][T]; Y: [bh][T][D]
__global__ __launch_bounds__(256, 2) void attn_k(const u16* __restrict__ Q,
                                                 const u16* __restrict__ Kb,
                                                 const u16* __restrict__ Vtg,
                                                 u16* __restrict__ Y) {
    __shared__ __attribute__((aligned(16))) u16 Ks[128 * 64];       // [kcol][d], swizzle GM=7
    __shared__ __attribute__((aligned(16))) u16 Vs[64 * 128];       // [d][t],   swizzle GM=15
    __shared__ __attribute__((aligned(16))) u16 Ps[4][2][16 * 128]; // per-wave, per-sub
    const int tid  = threadIdx.x;
    const int lane = tid & 63, w = tid >> 6;
    const int quad = lane >> 4, l16 = lane & 15;
    const int p  = blockIdx.x;                 // 0..15
    const int bh = blockIdx.y;
    const int sub[2]  = {31 - p, p};           // hi (long), lo (short)
    const int nkt0 = ((31 - p) >> 1) + 1;      // k-tiles for hi
    const int nkt1 = (p >> 1) + 1;             // k-tiles for lo
    const size_t base  = (size_t)bh * TT * DD;
    const size_t baseV = (size_t)bh * DD * TT;

    // Q fragments (A-layout): wave owns rows sub*64 + w*16 + l16
    bf16x8 qf[2][2];
    for (int s = 0; s < 2; s++)
        for (int kk = 0; kk < 2; kk++)
            qf[s][kk] = *(const bf16x8*)(Q + base +
                (size_t)(sub[s] * 64 + w * 16 + l16) * DD + kk * 32 + quad * 8);

    float mst[2][4], lst[2][4];
    f32x4 oacc[2][4];
    for (int s = 0; s < 2; s++)
        for (int r = 0; r < 4; r++) { mst[s][r] = -1e30f; lst[s][r] = 0.f; }
    for (int s = 0; s < 2; s++)
        for (int nd = 0; nd < 4; nd++)
            for (int e = 0; e < 4; e++) oacc[s][nd][e] = 0.f;

    const float SC = 0.125f * 1.44269504f;     // 1/sqrt(D) * log2(e)

    // one S+softmax pass for subtile s against the staged k-tile jk
    auto pass = [&](int s, int jk) {
        const int sb = sub[s];
        f32x4 sacc[8];
        for (int ni = 0; ni < 8; ni++)
            for (int e = 0; e < 4; e++) sacc[ni][e] = 0.f;
        for (int kk = 0; kk < 2; kk++)
            for (int ni = 0; ni < 8; ni++) {
                int row = ni * 16 + l16;
                bf16x8 kf = *(const bf16x8*)&Ks[row * 64 +
                    (((kk * 4 + quad) ^ (row & 7)) << 3)];
                sacc[ni] = __builtin_amdgcn_mfma_f32_16x16x32_bf16(
                    qf[s][kk], kf, sacc[ni], 0, 0, 0);
            }
        for (int ni = 0; ni < 8; ni++)
            for (int r = 0; r < 4; r++) sacc[ni][r] *= SC;
        if (jk == (sb >> 1)) {                 // diagonal tile: causal mask
            int gr0 = sb * 64 + w * 16 + quad * 4;
            for (int ni = 0; ni < 8; ni++)
                for (int r = 0; r < 4; r++) {
                    int gc = jk * 128 + ni * 16 + l16;
                    if (gc > gr0 + r) sacc[ni][r] = -1e30f;
                }
        }
        float alpha[4], rowsum[4];
        for (int r = 0; r < 4; r++) {
            float mx = sacc[0][r];
            for (int ni = 1; ni < 8; ni++) mx = fmaxf(mx, sacc[ni][r]);
            for (int off = 8; off >= 1; off >>= 1)
                mx = fmaxf(mx, __shfl_xor(mx, off));
            float mn = fmaxf(mst[s][r], mx);
            alpha[r] = __builtin_amdgcn_exp2f(mst[s][r] - mn);
            mst[s][r] = mn;
            rowsum[r] = 0.f;
        }
        for (int ni = 0; ni < 8; ni++)
            for (int r = 0; r < 4; r++) {
                float pv = __builtin_amdgcn_exp2f(sacc[ni][r] - mst[s][r]);
                rowsum[r] += pv;
                int row = quad * 4 + r;                // Ps row 0..15
                int cg  = ni * 2 + (l16 >> 3);
                Ps[w][s][row * 128 + ((cg ^ row) << 3) + (l16 & 7)] = f2b_fast(pv);
            }
        for (int r = 0; r < 4; r++) {
            float sm = rowsum[r];
            for (int off = 8; off >= 1; off >>= 1)
                sm += __shfl_xor(sm, off);
            lst[s][r] = lst[s][r] * alpha[r] + sm;
            for (int nd = 0; nd < 4; nd++) oacc[s][nd][r] *= alpha[r];
        }
    };

    int4 kreg[4], vreg[4];
    // prefetch k-tile 0
    for (int i = 0; i < 4; i++) {
        int c = i * 256 + tid;
        int rk = c >> 3, gk = c & 7;
        kreg[i] = *(const int4*)(Kb + base + (size_t)rk * DD + gk * 8);
        int rv = c >> 4, gv = c & 15;
        vreg[i] = *(const int4*)(Vtg + baseV + (size_t)rv * TT + gv * 8);
    }

    for (int jk = 0; jk < nkt0; ++jk) {
        __syncthreads();                       // all waves done reading prior tile
        for (int i = 0; i < 4; i++) {
            int c = i * 256 + tid;
            int rk = c >> 3, gk = c & 7;
            *(int4*)&Ks[rk * 64 + ((gk ^ (rk & 7)) << 3)] = kreg[i];
            int rv = c >> 4, gv = c & 15;
            *(int4*)&Vs[rv * 128 + ((gv ^ (rv & 15)) << 3)] = vreg[i];
        }
        __syncthreads();
        if (jk + 1 < nkt0) {                   // prefetch next tile behind compute
            int k0n = (jk + 1) * 128;
            for (int i = 0; i < 4; i++) {
                int c = i * 256 + tid;
                int rk = c >> 3, gk = c & 7;
                kreg[i] = *(const int4*)(Kb + base + (size_t)(k0n + rk) * DD + gk * 8);
                int rv = c >> 4, gv = c & 15;
                vreg[i] = *(const int4*)(Vtg + baseV + (size_t)rv * TT + k0n + gv * 8);
            }
        }
        const bool both = (jk < nkt1);
        pass(0, jk);
        if (both) pass(1, jk);

        // PV for both subtiles, sharing vf loads (Ps per-wave: no barrier needed)
        for (int kk = 0; kk < 4; kk++) {
            bf16x8 vf[4];
            for (int nd = 0; nd < 4; nd++) {
                int row = nd * 16 + l16;
                vf[nd] = *(const bf16x8*)&Vs[row * 128 +
                    (((kk * 4 + quad) ^ (row & 15)) << 3)];
            }
            {
                bf16x8 pf = *(const bf16x8*)&Ps[w][0][l16 * 128 +
                    (((kk * 4 + quad) ^ l16) << 3)];
                for (int nd = 0; nd < 4; nd++)
                    oacc[0][nd] = __builtin_amdgcn_mfma_f32_16x16x32_bf16(
                        pf, vf[nd], oacc[0][nd], 0, 0, 0);
            }
            if (both) {
                bf16x8 pf = *(const bf16x8*)&Ps[w][1][l16 * 128 +
                    (((kk * 4 + quad) ^ l16) << 3)];
                for (int nd = 0; nd < 4; nd++)
                    oacc[1][nd] = __builtin_amdgcn_mfma_f32_16x16x32_bf16(
                        pf, vf[nd], oacc[1][nd], 0, 0, 0);
            }
        }
    }

    for (int s = 0; s < 2; s++)
        for (int nd = 0; nd < 4; nd++)
            for (int r = 0; r < 4; r++) {
                int row = sub[s] * 64 + w * 16 + quad * 4 + r;
                int col = nd * 16 + l16;
                Y[base + (size_t)row * DD + col] = f2b(oacc[s][nd][r] / lst[s][r]);
            }
}

extern "C" void kernel_launch(void* const* d_in, const int* in_sizes, int n_in,
                              void* d_out, int out_size, void* d_ws, size_t ws_size,
                              hipStream_t stream) {
    const float* x      = (const float*)d_in[0];   // [2,2048,1024] fp32
    const float* W_attn = (const float*)d_in[1];   // [1024,3072]  fp32
    const float* W_proj = (const float*)d_in[2];   // [1024,1024]  fp32
    float* out = (float*)d_out;                    // [2,2048,1024] fp32

    u16* Wt_attn = (u16*)d_ws;                    // 3072*1024
    u16* Wt_proj = Wt_attn + 3072 * 1024;         // 1024*1024
    u16* xb      = Wt_proj + 1024 * 1024;         // 4096*1024 (reused as vt)
    u16* q       = xb + (size_t)MM * CC;
    u16* k       = q + (size_t)32 * 2048 * 64;
    u16* v       = k + (size_t)32 * 2048 * 64;
    u16* y       = v + (size_t)32 * 2048 * 64;
    u16* vt      = xb;                            // dead after gemm<0>

    cvt_x_k<<<dim3(MM * CC / 1024), 256, 0, stream>>>(x, xb);
    transpose_cvt_k<<<dim3(3072 / 64, 1024 / 64), dim3(64, 4), 0, stream>>>(
        W_attn, Wt_attn, 1024, 3072);
    transpose_cvt_k<<<dim3(1024 / 64, 1024 / 64), dim3(64, 4), 0, stream>>>(
        W_proj, Wt_proj, 1024, 1024);
    gemm_k<0><<<dim3(MM / 128, 3072 / 128), 256, 0, stream>>>(
        xb, Wt_attn, q, k, v, nullptr, 3072, 1024);
    transpose_v_k<<<dim3(TT / 64, BB * HH), dim3(64, 4), 0, stream>>>(v, vt);
    attn_k<<<dim3(16, BB * HH), 256, 0, stream>>>(q, k, vt, y);
    gemm_k<1><<<dim3(MM / 128, 1024 / 128), 256, 0, stream>>>(
        y, Wt_proj, nullptr, nullptr, nullptr, out, 1024, 1024);
}

// Round 7
// 270.447 us; speedup vs baseline: 1.4883x; 1.0562x over previous
//
#include <hip/hip_runtime.h>

typedef unsigned short u16;
typedef __bf16 bf16x8 __attribute__((ext_vector_type(8)));
typedef float f32x4 __attribute__((ext_vector_type(4)));

#define BB 2
#define TT 2048
#define CC 1024
#define HH 16
#define DD 64
#define MM (BB*TT)   // 4096

__device__ __forceinline__ u16 f2b(float f) {
    union { float f; unsigned int i; } a; a.f = f;
    unsigned int u = a.i;
    unsigned int r = (u + 0x7FFFu + ((u >> 16) & 1u)) >> 16;
    return (u16)r;
}
__device__ __forceinline__ u16 f2b_fast(float f) {
    union { float f; unsigned int i; } a; a.f = f;
    return (u16)((a.i + 0x8000u) >> 16);
}

// async global -> LDS, 16B per lane (dest must be wave-uniform base + lane*16)
__device__ __forceinline__ void gld16(const u16* g, u16* l) {
    __builtin_amdgcn_global_load_lds(
        (const __attribute__((address_space(1))) unsigned int*)g,
        (__attribute__((address_space(3))) unsigned int*)l, 16, 0, 0);
}

// ---------------- fp32 -> bf16 elementwise ----------------
__global__ __launch_bounds__(256) void cvt_x_k(const float* __restrict__ in,
                                               u16* __restrict__ out) {
    int i = blockIdx.x * 256 + threadIdx.x;
    float4 v = ((const float4*)in)[i];
    ushort4 o;
    o.x = f2b(v.x); o.y = f2b(v.y); o.z = f2b(v.z); o.w = f2b(v.w);
    ((ushort4*)out)[i] = o;
}

// ------ fp32 [K,N] -> bf16 [N,K] transpose+convert ------
__global__ __launch_bounds__(256) void transpose_cvt_k(const float* __restrict__ in,
                                                       u16* __restrict__ out,
                                                       int K, int N) {
    __shared__ u16 tile[64][65];
    int n0 = blockIdx.x * 64, k0 = blockIdx.y * 64;
    int tx = threadIdx.x, ty = threadIdx.y;   // (64,4)
    for (int i = 0; i < 16; i++) {
        int row = ty + i * 4;
        tile[row][tx] = f2b(in[(size_t)(k0 + row) * N + n0 + tx]);
    }
    __syncthreads();
    for (int i = 0; i < 16; i++) {
        int row = ty + i * 4;
        out[(size_t)(n0 + row) * K + k0 + tx] = tile[tx][row];
    }
}

// ------ bf16 per-bh transpose: v[bh][T][D] -> vt[bh][D][T] ------
__global__ __launch_bounds__(256) void transpose_v_k(const u16* __restrict__ in,
                                                     u16* __restrict__ out) {
    __shared__ u16 tile[64][65];
    int t0 = blockIdx.x * 64, bh = blockIdx.y;
    const u16* src = in + (size_t)bh * TT * DD;
    u16* dst = out + (size_t)bh * DD * TT;
    int tx = threadIdx.x, ty = threadIdx.y;
    for (int i = 0; i < 16; i++) {
        int row = ty + i * 4;
        tile[row][tx] = src[(size_t)(t0 + row) * DD + tx];
    }
    __syncthreads();
    for (int i = 0; i < 16; i++) {
        int row = ty + i * 4;
        dst[(size_t)row * TT + t0 + tx] = tile[tx][row];
    }
}

// ---------------- GEMM: C[M,N] = A[M,K] * Bt[N,K]^T ----------------
// MODE 0 epilogue pre-scales q by 0.125*log2(e) for the attn log2-softmax.
template<int MODE>
__global__ __launch_bounds__(256) void gemm_k(const u16* __restrict__ A,
                                              const u16* __restrict__ Bt,
                                              u16* __restrict__ Cq,
                                              u16* __restrict__ Ck,
                                              u16* __restrict__ Cv,
                                              float* __restrict__ Cout,
                                              int N, int K) {
    __shared__ __attribute__((aligned(16))) u16 As[128 * 32];
    __shared__ __attribute__((aligned(16))) u16 Bs[128 * 32];
    const int tid  = threadIdx.x;
    const int lane = tid & 63, w = tid >> 6;
    const int wm = w >> 1, wn = w & 1;
    const int quad = lane >> 4, l16 = lane & 15;
    const int m0 = blockIdx.x * 128, n0 = blockIdx.y * 128;

    f32x4 acc[4][4];
    for (int mi = 0; mi < 4; mi++)
        for (int ni = 0; ni < 4; ni++)
            for (int e = 0; e < 4; e++) acc[mi][ni][e] = 0.f;

    for (int k0 = 0; k0 < K; k0 += 32) {
        for (int i = 0; i < 2; i++) {
            int c = tid + 256 * i;
            int row = c >> 2, col = (c & 3) * 8;
            const u16* srcA;
            if constexpr (MODE == 0) {
                srcA = A + (size_t)(m0 + row) * K + k0 + col;
            } else {
                int m = m0 + row;
                int b = m >> 11, t = m & 2047;
                int kk = k0 + col;
                int h = kk >> 6, d = kk & 63;
                srcA = A + ((size_t)(b * HH + h) * TT + t) * DD + d;
            }
            gld16(srcA, &As[c * 8]);
            gld16(Bt + (size_t)(n0 + row) * K + k0 + col, &Bs[c * 8]);
        }
        __syncthreads();
        bf16x8 af[4], bfm[4];
        for (int mi = 0; mi < 4; mi++)
            af[mi] = *(const bf16x8*)&As[(wm * 64 + mi * 16 + l16) * 32 + quad * 8];
        for (int ni = 0; ni < 4; ni++)
            bfm[ni] = *(const bf16x8*)&Bs[(wn * 64 + ni * 16 + l16) * 32 + quad * 8];
        for (int mi = 0; mi < 4; mi++)
            for (int ni = 0; ni < 4; ni++)
                acc[mi][ni] = __builtin_amdgcn_mfma_f32_16x16x32_bf16(
                    af[mi], bfm[ni], acc[mi][ni], 0, 0, 0);
        __syncthreads();
    }

    const float SCQ = 0.125f * 1.44269504f;
    for (int mi = 0; mi < 4; mi++)
        for (int ni = 0; ni < 4; ni++)
            for (int r = 0; r < 4; r++) {
                int row = m0 + wm * 64 + mi * 16 + quad * 4 + r;
                int col = n0 + wn * 64 + ni * 16 + l16;
                if constexpr (MODE == 0) {
                    int which = col >> 10;
                    int h = (col >> 6) & 15, d = col & 63;
                    int b = row >> 11, t = row & 2047;
                    size_t off = ((size_t)(b * HH + h) * TT + t) * DD + d;
                    float val = acc[mi][ni][r];
                    if (which == 0) val *= SCQ;
                    (which == 0 ? Cq : which == 1 ? Ck : Cv)[off] = f2b(val);
                } else {
                    Cout[(size_t)row * N + col] = acc[mi][ni][r];
                }
            }
}

// ---------------- flash attention v4: barrier-free, K/V streamed ----------------
// Block (p, bh): q-subtiles {31-p, p}; 17 tile-passes for every p (balanced).
// K fragments read directly from K [bh][T][D]; V fragments from Vt [bh][D][T].
// All 4 waves load identical kf/vf addresses -> L1 dedup. Only Ps lives in LDS
// (per-wave -> NO __syncthreads anywhere).
__global__ __launch_bounds__(256, 2) void attn_k(const u16* __restrict__ Q,
                                                 const u16* __restrict__ Kb,
                                                 const u16* __restrict__ Vtg,
                                                 u16* __restrict__ Y) {
    __shared__ __attribute__((aligned(16))) u16 Ps[4][2][16 * 128];   // 32 KB
    const int tid  = threadIdx.x;
    const int lane = tid & 63, w = tid >> 6;
    const int quad = lane >> 4, l16 = lane & 15;
    const int p  = blockIdx.x;                 // 0..15
    const int bh = blockIdx.y;
    const int sub[2] = {31 - p, p};
    const int nkt0 = ((31 - p) >> 1) + 1;
    const int nkt1 = (p >> 1) + 1;             // nkt1 <= 8 < 9 <= nkt0
    const size_t base  = (size_t)bh * TT * DD;
    const size_t baseV = (size_t)bh * DD * TT;

    // Q fragments (A-layout, pre-scaled by 0.125*log2e in gemm0 epilogue)
    bf16x8 qf[2][2];
    for (int s = 0; s < 2; s++)
        for (int kk = 0; kk < 2; kk++)
            qf[s][kk] = *(const bf16x8*)(Q + base +
                (size_t)(sub[s] * 64 + w * 16 + l16) * DD + kk * 32 + quad * 8);

    float mst[2][4], lst[2][4];
    f32x4 oacc[2][4];
    for (int s = 0; s < 2; s++)
        for (int r = 0; r < 4; r++) { mst[s][r] = -1e30f; lst[s][r] = 0.f; }
    for (int s = 0; s < 2; s++)
        for (int nd = 0; nd < 4; nd++)
            for (int e = 0; e < 4; e++) oacc[s][nd][e] = 0.f;

    for (int jk = 0; jk < nkt0; jk++) {
        const bool both = (jk < nkt1);
        const u16* kb = Kb + base + (size_t)(jk * 128) * DD;

        // ---- S = Q K^T for one (or two) 64x128 subtiles, kf streamed ----
        f32x4 s0[8], s1[8];
        for (int ni = 0; ni < 8; ni++)
            for (int e = 0; e < 4; e++) { s0[ni][e] = 0.f; s1[ni][e] = 0.f; }
        if (both) {
            for (int kk = 0; kk < 2; kk++) {
                bf16x8 kfa[8];
                for (int ni = 0; ni < 8; ni++)
                    kfa[ni] = *(const bf16x8*)(kb +
                        (size_t)(ni * 16 + l16) * DD + kk * 32 + quad * 8);
                for (int ni = 0; ni < 8; ni++) {
                    s0[ni] = __builtin_amdgcn_mfma_f32_16x16x32_bf16(
                        qf[0][kk], kfa[ni], s0[ni], 0, 0, 0);
                    s1[ni] = __builtin_amdgcn_mfma_f32_16x16x32_bf16(
                        qf[1][kk], kfa[ni], s1[ni], 0, 0, 0);
                }
            }
        } else {
            for (int kk = 0; kk < 2; kk++) {
                bf16x8 kfa[8];
                for (int ni = 0; ni < 8; ni++)
                    kfa[ni] = *(const bf16x8*)(kb +
                        (size_t)(ni * 16 + l16) * DD + kk * 32 + quad * 8);
                for (int ni = 0; ni < 8; ni++)
                    s0[ni] = __builtin_amdgcn_mfma_f32_16x16x32_bf16(
                        qf[0][kk], kfa[ni], s0[ni], 0, 0, 0);
            }
        }

        // ---- online softmax (log2 domain) + Ps write, per sub ----
        for (int s = 0; s < 2; s++) {
            if (s == 1 && !both) break;
            f32x4* sc = (s == 0) ? s0 : s1;
            const int sb = sub[s];
            if (jk == (sb >> 1)) {             // diagonal tile: causal mask
                int row0 = sb * 64 + w * 16 + quad * 4;
                int col0 = jk * 128 + l16;
                for (int ni = 0; ni < 8; ni++)
                    for (int r = 0; r < 4; r++)
                        if (col0 + ni * 16 > row0 + r) sc[ni][r] = -1e30f;
            }
            float alpha[4];
            for (int r = 0; r < 4; r++) {
                float mx = sc[0][r];
                for (int ni = 1; ni < 8; ni++) mx = fmaxf(mx, sc[ni][r]);
                for (int off = 8; off >= 1; off >>= 1)
                    mx = fmaxf(mx, __shfl_xor(mx, off));
                float mn = fmaxf(mst[s][r], mx);
                alpha[r] = __builtin_amdgcn_exp2f(mst[s][r] - mn);
                mst[s][r] = mn;
            }
            float rs[4] = {0.f, 0.f, 0.f, 0.f};
            for (int ni = 0; ni < 8; ni++)
                for (int r = 0; r < 4; r++) {
                    float pv = __builtin_amdgcn_exp2f(sc[ni][r] - mst[s][r]);
                    rs[r] += pv;
                    int row = quad * 4 + r;
                    int cg  = ni * 2 + (l16 >> 3);
                    Ps[w][s][row * 128 + ((cg ^ row) << 3) + (l16 & 7)] =
                        f2b_fast(pv);
                }
            for (int r = 0; r < 4; r++) {
                float sm = rs[r];
                for (int off = 8; off >= 1; off >>= 1)
                    sm += __shfl_xor(sm, off);
                lst[s][r] = lst[s][r] * alpha[r] + sm;
                for (int nd = 0; nd < 4; nd++) oacc[s][nd][r] *= alpha[r];
            }
        }

        // ---- O += P V, vf streamed from Vt [bh][D][T] ----
        const u16* vb = Vtg + baseV + jk * 128;
        for (int kk = 0; kk < 4; kk++) {
            bf16x8 vfa[4];
            for (int nd = 0; nd < 4; nd++)
                vfa[nd] = *(const bf16x8*)(vb +
                    (size_t)(nd * 16 + l16) * TT + kk * 32 + quad * 8);
            bf16x8 pf0 = *(const bf16x8*)&Ps[w][0][l16 * 128 +
                (((kk * 4 + quad) ^ l16) << 3)];
            for (int nd = 0; nd < 4; nd++)
                oacc[0][nd] = __builtin_amdgcn_mfma_f32_16x16x32_bf16(
                    pf0, vfa[nd], oacc[0][nd], 0, 0, 0);
            if (both) {
                bf16x8 pf1 = *(const bf16x8*)&Ps[w][1][l16 * 128 +
                    (((kk * 4 + quad) ^ l16) << 3)];
                for (int nd = 0; nd < 4; nd++)
                    oacc[1][nd] = __builtin_amdgcn_mfma_f32_16x16x32_bf16(
                        pf1, vfa[nd], oacc[1][nd], 0, 0, 0);
            }
        }
    }

    for (int s = 0; s < 2; s++)
        for (int nd = 0; nd < 4; nd++)
            for (int r = 0; r < 4; r++) {
                int row = sub[s] * 64 + w * 16 + quad * 4 + r;
                int col = nd * 16 + l16;
                Y[base + (size_t)row * DD + col] = f2b(oacc[s][nd][r] / lst[s][r]);
            }
}

extern "C" void kernel_launch(void* const* d_in, const int* in_sizes, int n_in,
                              void* d_out, int out_size, void* d_ws, size_t ws_size,
                              hipStream_t stream) {
    const float* x      = (const float*)d_in[0];   // [2,2048,1024] fp32
    const float* W_attn = (const float*)d_in[1];   // [1024,3072]  fp32
    const float* W_proj = (const float*)d_in[2];   // [1024,1024]  fp32
    float* out = (float*)d_out;                    // [2,2048,1024] fp32

    u16* Wt_attn = (u16*)d_ws;                    // 3072*1024
    u16* Wt_proj = Wt_attn + 3072 * 1024;         // 1024*1024
    u16* xb      = Wt_proj + 1024 * 1024;         // 4096*1024 (reused as vt)
    u16* q       = xb + (size_t)MM * CC;
    u16* k       = q + (size_t)32 * 2048 * 64;
    u16* v       = k + (size_t)32 * 2048 * 64;
    u16* y       = v + (size_t)32 * 2048 * 64;
    u16* vt      = xb;                            // dead after gemm<0>

    cvt_x_k<<<dim3(MM * CC / 1024), 256, 0, stream>>>(x, xb);
    transpose_cvt_k<<<dim3(3072 / 64, 1024 / 64), dim3(64, 4), 0, stream>>>(
        W_attn, Wt_attn, 1024, 3072);
    transpose_cvt_k<<<dim3(1024 / 64, 1024 / 64), dim3(64, 4), 0, stream>>>(
        W_proj, Wt_proj, 1024, 1024);
    gemm_k<0><<<dim3(MM / 128, 3072 / 128), 256, 0, stream>>>(
        xb, Wt_attn, q, k, v, nullptr, 3072, 1024);
    transpose_v_k<<<dim3(TT / 64, BB * HH), dim3(64, 4), 0, stream>>>(v, vt);
    attn_k<<<dim3(16, BB * HH), 256, 0, stream>>>(q, k, vt, y);
    gemm_k<1><<<dim3(MM / 128, 1024 / 128), 256, 0, stream>>>(
        y, Wt_proj, nullptr, nullptr, nullptr, out, 1024, 1024);
}